// Round 2
// baseline (228.320 us; speedup 1.0000x reference)
//
#include <hip/hip_runtime.h>

typedef __attribute__((ext_vector_type(8))) short bf16x8;
typedef __attribute__((ext_vector_type(4))) float f32x4;
typedef unsigned int u32;

__device__ __forceinline__ unsigned short f2bf(float f) {
  union { float f; unsigned int u; } a; a.f = f;
  unsigned int u = a.u;
  u += 0x7FFFu + ((u >> 16) & 1u);   // RNE
  return (unsigned short)(u >> 16);
}

// async global->LDS, 16B per lane. LDS dest = wave-uniform base + lane*16.
__device__ __forceinline__ void gload16(const unsigned short* g, unsigned short* l) {
  __builtin_amdgcn_global_load_lds((const __attribute__((address_space(1))) u32*)g,
                                   (__attribute__((address_space(3))) u32*)l, 16, 0, 0);
}

#define BK 64
// Verified invariants: XOR chunk swizzle phys = c ^ (row&7) on 128B LDS rows ->
// 0 bank conflicts (R2..R10); 128 unified regs -> 4 waves/SIMD (R7); no-max
// softmax with E=exp(s)+rsum in scores epilogue (R8); scores tri-grid 128x64 +
// PV stripe-pairing (R10).
//
// R12 algebra (R11 fixed): scores = X (Wq Wk^T) X^T. With gemm C[m][n] =
// sum_k A[m][k] B[n][k], feeding A=Wk, B=Wq in ORIGINAL [in][out] row-major
// gives C[j][i] = sum_o Wk[j][o] Wq[i][o] = M[i][j] = TVB[j][i] as the TV GEMM
// needs (R11 bug: fed transposed weights -> contracted over the input dim).

// C = A[M][K] * B[N][K]^T, bf16 in, fp32 accum.
// MODE 1: plain bf16 GEMM out (Mt), 128x64 tile, out stride 1024
// MODE 2: scores->E, 128x64 tile: bf16 exp(C*scale) masked col<=row, stride 2048;
//         compact triangular grid; row sums atomicAdd into Cf (rsum)
// MODE 3: PV, 128x64 tile, stripe pairs: blockIdx.y = p; seg0 = stripe 15-p
//         (K=128*(16-p)), seg1 = stripe p (K=128*(p+1)); out = C / rsum[row]
template<int MODE>
__global__ __launch_bounds__(256, 4)
void gemm_bt(const unsigned short* __restrict__ A,
             const unsigned short* __restrict__ Bm,
             float* __restrict__ Cf,
             float* __restrict__ Cf2,
             unsigned short* __restrict__ Cb,
             int K, long aBatch, long bBatch, long cBatch, float scale)
{
  constexpr int NI    = (MODE == 0) ? 4 : 2;    // 16-row MFMA tiles per wave (m)
  constexpr int TNc   = (MODE == 0) ? 128 : 64; // block n-extent
  constexpr int BROWS = (MODE == 0) ? 32 : 16;  // B rows staged per wave
  constexpr int BG    = (MODE == 0) ? 4 : 2;    // B gloads per wave

  int z = blockIdx.z;
  A  += (long)z * aBatch;
  Bm += (long)z * bBatch;
  if (MODE == 2) { Cb += (long)z * cBatch; Cf += (long)z * 2048; }
  if (MODE == 3) { Cf += (long)z * cBatch; Cf2 += (long)z * 2048; }

  int bm0 = 0, bn, p = 0;
  if (MODE == 2) {
    // triangular decode over 128x64 tiles: cum C(r) = r(r+1), 272 tiles/batch
    int f = blockIdx.x;
    int r = (int)((sqrtf((float)(4 * f + 1)) - 1.0f) * 0.5f);
    while ((r + 1) * (r + 2) <= f) r++;
    while (r * (r + 1) > f) r--;
    bm0 = r * 128;
    bn  = (f - r * (r + 1)) * 64;
  } else if (MODE == 3) {
    p  = blockIdx.y;
    bn = blockIdx.x * 64;
  } else {
    bm0 = blockIdx.y * 128;
    bn  = blockIdx.x * TNc;
  }

  __shared__ __align__(16) unsigned short As[128 * BK];
  __shared__ __align__(16) unsigned short Bs[TNc * BK];

  int tid  = threadIdx.x;
  int wave = tid >> 6, lane = tid & 63;
  int wm = (MODE == 0) ? (wave >> 1) * 64 : wave * 32;
  int wn = (MODE == 0) ? (wave & 1) * 64 : 0;
  int quad = lane >> 4, l16 = lane & 15;

  // staging lane coords: 8-row groups, chunk XOR-swizzled (row%8-invariant)
  int r8 = lane >> 3;
  int c  = (lane & 7) ^ r8;
  const unsigned short* Bg = Bm + (long)(bn + wave * BROWS + r8) * K + c * 8;
  unsigned short* Al = &As[(wave * 32) * BK];
  unsigned short* Bl = &Bs[(wave * BROWS) * BK];

  const int nseg = (MODE == 3) ? 2 : 1;
  for (int seg = 0; seg < nseg; seg++) {
    int bm   = (MODE == 3) ? ((seg == 0) ? (15 - p) * 128 : p * 128) : bm0;
    int Keff = (MODE == 3) ? ((seg == 0) ? 128 * (16 - p) : 128 * (p + 1)) : K;
    const unsigned short* Ag = A + (long)(bm + wave * 32 + r8) * K + c * 8;

    f32x4 acc[NI][4] = {};

    for (int k0 = 0; k0 < Keff; k0 += BK) {
#pragma unroll
      for (int g = 0; g < 4; g++)
        gload16(Ag + k0 + (long)g * 8 * K, Al + g * 8 * BK);
#pragma unroll
      for (int g = 0; g < BG; g++)
        gload16(Bg + k0 + (long)g * 8 * K, Bl + g * 8 * BK);
      __syncthreads();

#pragma unroll
      for (int h = 0; h < 2; h++) {
        bf16x8 af[NI], bfr[4];
#pragma unroll
        for (int i = 0; i < NI; i++)
          af[i]  = *(const bf16x8*)&As[(wm + i * 16 + l16) * BK + (((quad + 4 * h) ^ (l16 & 7)) * 8)];
#pragma unroll
        for (int j = 0; j < 4; j++)
          bfr[j] = *(const bf16x8*)&Bs[(wn + j * 16 + l16) * BK + (((quad + 4 * h) ^ (l16 & 7)) * 8)];
#pragma unroll
        for (int i = 0; i < NI; i++)
#pragma unroll
          for (int j = 0; j < 4; j++)
            acc[i][j] = __builtin_amdgcn_mfma_f32_16x16x32_bf16(af[i], bfr[j], acc[i][j], 0, 0, 0);
      }
      __syncthreads();
    }

    // Epilogue. C/D layout: col = lane&15, row = quad*4 + reg  [m89/m91]
#pragma unroll
    for (int i = 0; i < NI; i++) {
      int grow0 = bm + wm + i * 16 + quad * 4;
      if (MODE == 2) {
#pragma unroll
        for (int r = 0; r < 4; r++) {
          int grow = grow0 + r;
          float rowpart = 0.f;
#pragma unroll
          for (int j = 0; j < 4; j++) {
            int gcol = bn + j * 16 + l16;
            float e = (gcol <= grow) ? __expf(acc[i][j][r] * scale) : 0.f;
            rowpart += e;
            Cb[(long)grow * 2048 + gcol] = f2bf(e);
          }
          rowpart += __shfl_xor(rowpart, 1);
          rowpart += __shfl_xor(rowpart, 2);
          rowpart += __shfl_xor(rowpart, 4);
          rowpart += __shfl_xor(rowpart, 8);
          if (l16 == 0) atomicAdd(&Cf[grow], rowpart);
        }
      } else if (MODE == 3) {
        float rinv[4];
#pragma unroll
        for (int r = 0; r < 4; r++) rinv[r] = 1.0f / Cf2[grow0 + r];
#pragma unroll
        for (int j = 0; j < 4; j++) {
          int gcol = bn + j * 16 + l16;
#pragma unroll
          for (int r = 0; r < 4; r++)
            Cf[(long)(grow0 + r) * 1024 + gcol] = acc[i][j][r] * rinv[r];
        }
      } else if (MODE == 1) {
#pragma unroll
        for (int j = 0; j < 4; j++) {
          int gcol = bn + j * 16 + l16;
#pragma unroll
          for (int r = 0; r < 4; r++)
            Cb[(long)(grow0 + r) * 1024 + gcol] = f2bf(acc[i][j][r]);
        }
      } else {                          // MODE 0: TV split epilogue
#pragma unroll
        for (int j = 0; j < 4; j++) {
          int gcol = bn + wn + j * 16 + l16;
          int which = gcol >> 10;       // block-uniform (bn multiple of 128)
          int col = gcol & 1023;
          if (which == 0) {             // T bf16 row-major [8192][1024]
#pragma unroll
            for (int r = 0; r < 4; r++)
              Cb[(long)(grow0 + r) * 1024 + col] = f2bf(acc[i][j][r]);
          } else {                      // Vt[b][col][s], 4-row pack along s
            unsigned short* Vt = Cb + (long)8192 * 1024;
            int bb = grow0 >> 11, s = grow0 & 2047;
            ushort4 pk;
            pk.x = f2bf(acc[i][j][0]); pk.y = f2bf(acc[i][j][1]);
            pk.z = f2bf(acc[i][j][2]); pk.w = f2bf(acc[i][j][3]);
            *(ushort4*)(Vt + ((long)bb * 1024 + col) * 2048 + s) = pk;
          }
        }
      }
    }
  }
}

// R13/R14: fused TV on the 256x256 deep-pipelined schedule (T3+T4 counted
// vmcnt, T5 setprio). 512 thr = 8 waves (2m x 4n), per-wave out 128x64,
// acc 8x4 f32x4. K split into 32-wide slices, 4 LDS slots (4 x (256x32 A +
// 256x32 B) bf16 = 128 KiB, 1 block/CU). Pipeline: prefetch depth 3; phase s:
// issue slice s+3 (slot (s-1)&3, whose last reader drained lgkmcnt(0) before
// phase s-1's barrier), ds_read slice s, 32 MFMA, then s_waitcnt vmcnt(8)
// (slices s+2,s+3 in flight -> s+1 landed) + raw s_barrier. vmcnt never
// drains to 0 in the main loop; drains over the last 3 phases only
// (s=29: vmcnt(4), s=30: vmcnt(0)). Staging swizzle: 64B rows, phys chunk =
// chunk ^ ((row>>1)&3), applied on the gload SOURCE (LDS dest is linear
// lane*16) and reproduced on the ds_read side -> <=2-way bank aliasing (free).
// R14 hardening: sched_barrier(0) after every inline-asm waitcnt (rule #18
// class: hipcc may hoist register-only ops past asm waits despite "memory").
__global__ __launch_bounds__(512, 2)
void gemm_tv(const unsigned short* __restrict__ A,   // Xb [8192][1024]
             const unsigned short* __restrict__ Bm,  // TVB [2048][1024]
             unsigned short* __restrict__ Cb)        // T ; Vt
{
  constexpr int SLICE = 32;                 // k per slice
  constexpr int SLOT  = 256 * SLICE;        // ushorts per operand slot
  __shared__ __align__(16) unsigned short As[4 * SLOT];
  __shared__ __align__(16) unsigned short Bs[4 * SLOT];

  const int tid  = threadIdx.x;
  const int wave = tid >> 6, lane = tid & 63;
  const int quad = lane >> 4, l16 = lane & 15;
  const int bm = blockIdx.y * 256;
  const int bn = blockIdx.x * 256;
  const int wm = (wave >> 2) * 128;         // wave rows: 2 x 128
  const int wn = (wave & 3) * 64;           // wave cols: 4 x 64

  // staging source lane coords: 16 rows x 4 chunks per gload, swizzled chunk
  const int srow = lane >> 2;
  const int sc   = ((lane & 3) ^ ((lane >> 3) & 3)) * 8;
  const unsigned short* Ag = A  + (long)(bm + wave * 32 + srow) * 1024 + sc;
  const unsigned short* Bg = Bm + (long)(bn + wave * 32 + srow) * 1024 + sc;
  unsigned short* Asl = As + wave * (32 * SLICE);   // wave-uniform LDS base
  unsigned short* Bsl = Bs + wave * (32 * SLICE);

  // frag read: logical k-chunk = quad; phys = quad ^ ((row>>1)&3).
  // row = wm + i*16 + l16 with wm,i*16 == 0 mod 8 -> (row>>1)&3 = (l16>>1)&3.
  const int pc = (quad ^ ((l16 >> 1) & 3)) * 8;

  f32x4 acc[8][4] = {};

#define STAGE(s)                                                          \
  { const int so_ = ((s) & 3) * SLOT; const int ko_ = (s) * SLICE;        \
    gload16(Ag + ko_,             Asl + so_);                             \
    gload16(Ag + ko_ + 16 * 1024, Asl + so_ + 16 * SLICE);                \
    gload16(Bg + ko_,             Bsl + so_);                             \
    gload16(Bg + ko_ + 16 * 1024, Bsl + so_ + 16 * SLICE); }

  STAGE(0) STAGE(1) STAGE(2)
  asm volatile("s_waitcnt vmcnt(8) lgkmcnt(0)" ::: "memory");  // slice 0 landed
  __builtin_amdgcn_sched_barrier(0);
  __builtin_amdgcn_s_barrier();

  constexpr int ns = 1024 / SLICE;          // 32 slices
#pragma unroll 1
  for (int s = 0; s < ns; ++s) {
    if (s + 3 < ns) STAGE(s + 3)
    const unsigned short* Asr = As + (s & 3) * SLOT;
    const unsigned short* Bsr = Bs + (s & 3) * SLOT;
    bf16x8 af[8], bfr[4];
#pragma unroll
    for (int i = 0; i < 8; ++i)
      af[i]  = *(const bf16x8*)&Asr[(wm + i * 16 + l16) * SLICE + pc];
#pragma unroll
    for (int j = 0; j < 4; ++j)
      bfr[j] = *(const bf16x8*)&Bsr[(wn + j * 16 + l16) * SLICE + pc];
    __builtin_amdgcn_s_setprio(1);
#pragma unroll
    for (int i = 0; i < 8; ++i)
#pragma unroll
      for (int j = 0; j < 4; ++j)
        acc[i][j] = __builtin_amdgcn_mfma_f32_16x16x32_bf16(af[i], bfr[j], acc[i][j], 0, 0, 0);
    __builtin_amdgcn_s_setprio(0);
    // lgkm already drained by MFMA consumption; kept as the sink guard.
    if (s < ns - 3)
      asm volatile("s_waitcnt vmcnt(8) lgkmcnt(0)" ::: "memory");
    else if (s == ns - 3)
      asm volatile("s_waitcnt vmcnt(4) lgkmcnt(0)" ::: "memory");
    else
      asm volatile("s_waitcnt vmcnt(0) lgkmcnt(0)" ::: "memory");
    __builtin_amdgcn_sched_barrier(0);
    __builtin_amdgcn_s_barrier();
  }
#undef STAGE

  // TV split epilogue (identical math to the verified MODE 0 path)
#pragma unroll
  for (int i = 0; i < 8; ++i) {
    int grow0 = bm + wm + i * 16 + quad * 4;
#pragma unroll
    for (int j = 0; j < 4; ++j) {
      int gcol = bn + wn + j * 16 + l16;
      int which = gcol >> 10;             // block-uniform (bn multiple of 256)
      int col = gcol & 1023;
      if (which == 0) {                   // T bf16 row-major [8192][1024]
#pragma unroll
        for (int r = 0; r < 4; r++)
          Cb[(long)(grow0 + r) * 1024 + col] = f2bf(acc[i][j][r]);
      } else {                            // Vt[b][col][s], 4-row pack along s
        unsigned short* Vt = Cb + (long)8192 * 1024;
        int bb = grow0 >> 11, ss = grow0 & 2047;
        ushort4 pk;
        pk.x = f2bf(acc[i][j][0]); pk.y = f2bf(acc[i][j][1]);
        pk.z = f2bf(acc[i][j][2]); pk.w = f2bf(acc[i][j][3]);
        *(ushort4*)(Vt + ((long)bb * 1024 + col) * 2048 + ss) = pk;
      }
    }
  }
}

// fused prep: [0,8192) x->bf16; [8192,9216) Wq->bf16 (NO transpose);
// [9216,10240) Wk->bf16 (NO transpose); [10240,11264) Wv transpose-convert;
// [11264,11272) zero rsum
__global__ __launch_bounds__(256)
void prep(const float* __restrict__ x,
          const float* __restrict__ W0, const float* __restrict__ W1,
          const float* __restrict__ W2,
          unsigned short* __restrict__ Xb,
          unsigned short* __restrict__ Wqb, unsigned short* __restrict__ Wkb,
          unsigned short* __restrict__ WvT,
          float* __restrict__ rsum)
{
  __shared__ float tile[32][33];
  int b = blockIdx.x;
  if (b < 8192) {
    long i = ((long)b * 256 + threadIdx.x) * 4;
    float4 v = *(const float4*)(x + i);
    ushort4 o;
    o.x = f2bf(v.x); o.y = f2bf(v.y); o.z = f2bf(v.z); o.w = f2bf(v.w);
    *(ushort4*)(Xb + i) = o;
  } else if (b < 10240) {
    int t = b - 8192;
    const float* W    = (t < 1024) ? W0 : W1;
    unsigned short* D = (t < 1024) ? Wqb : Wkb;
    long i = ((long)(t & 1023) * 256 + threadIdx.x) * 4;
    float4 v = *(const float4*)(W + i);
    ushort4 o;
    o.x = f2bf(v.x); o.y = f2bf(v.y); o.z = f2bf(v.z); o.w = f2bf(v.w);
    *(ushort4*)(D + i) = o;
  } else if (b < 11264) {
    int q = b - 10240;
    int kb = (q >> 5) * 32, nb = (q & 31) * 32;
    int tx = threadIdx.x & 31, ty = threadIdx.x >> 5;
    for (int r = ty; r < 32; r += 8)
      tile[r][tx] = W2[(long)(kb + r) * 1024 + nb + tx];
    __syncthreads();
    for (int r = ty; r < 32; r += 8)
      WvT[(long)(nb + r) * 1024 + kb + tx] = f2bf(tile[tx][r]);
  } else {
    long i = ((long)(b - 11264) * 256 + threadIdx.x) * 4;
    float4 zz = {0.f, 0.f, 0.f, 0.f};
    *(float4*)(rsum + i) = zz;
  }
}

extern "C" void kernel_launch(void* const* d_in, const int* in_sizes, int n_in,
                              void* d_out, int out_size, void* d_ws, size_t ws_size,
                              hipStream_t stream) {
  const float* x  = (const float*)d_in[0];
  const float* Wq = (const float*)d_in[1];
  const float* Wk = (const float*)d_in[2];
  const float* Wv = (const float*)d_in[3];
  float* out = (float*)d_out;

  // workspace layout (bf16 = unsigned short), ~120 MB
  unsigned short* Xb  = (unsigned short*)d_ws;            // [8192][1024]
  unsigned short* Wqb = Xb  + (long)8192 * 1024;          // [1024][1024] bf16 [in][out]
  unsigned short* Wkb = Wqb + (long)1024 * 1024;          // [1024][1024] bf16 [in][out]
  unsigned short* TVB = Wkb + (long)1024 * 1024;          // [2048][1024]: Mt ; WvT
  unsigned short* T   = TVB + (long)2048 * 1024;          // [8192][1024]
  unsigned short* Vt  = T   + (long)8192 * 1024;          // [4][1024][2048] (follows T!)
  unsigned short* E   = Vt  + (long)8192 * 1024;          // [4][2048][2048] bf16 exp(s)
  float* rsum         = (float*)(E + (long)4 * 2048 * 2048); // [4][2048] fp32

  prep<<<11272, 256, 0, stream>>>(x, Wq, Wk, Wv, Xb, Wqb, Wkb,
                                  TVB + (long)1024 * 1024, rsum);

  // Mt[j][i] = sum_o Wk[j][o] Wq[i][o] = M[i][j], M = Wq Wk^T
  gemm_bt<1><<<dim3(16, 8, 1), 256, 0, stream>>>(Wkb, Wqb, nullptr, nullptr, TVB,
      1024, 0, 0, 0, 1.f);

  // fused TV: [8192x2048] = Xb * [Mt;WvT]^T on the pipelined 256^2 schedule
  gemm_tv<<<dim3(8, 32, 1), 512, 0, stream>>>(Xb, TVB, T);

  // E = exp(T * Xb^T / 32) masked lower-tri + row sums; 272 tri-tiles per batch
  gemm_bt<2><<<dim3(272, 1, 4), 256, 0, stream>>>(T, Xb, rsum, nullptr, E, 1024,
      (long)2048 * 1024, (long)2048 * 1024, (long)2048 * 2048, 0.03125f);

  // out = (E * Vt^T)/rsum; stripe pairs (15-p, p) -> uniform 34-iter blocks
  gemm_bt<3><<<dim3(16, 8, 4), 256, 0, stream>>>(E, Vt, out, rsum, nullptr, 2048,
      (long)2048 * 2048, (long)1024 * 2048, (long)2048 * 1024, 1.f);
}